// Round 1
// 276.242 us; speedup vs baseline: 1.0624x; 1.0624x over previous
//
#include <hip/hip_runtime.h>
#include <stdint.h>

typedef __attribute__((ext_vector_type(8))) short bf16x8;   // 8 bf16 = 4 VGPR (MFMA A/B frag)
typedef __attribute__((ext_vector_type(4))) float f32x4;    // MFMA C/D frag
typedef __attribute__((ext_vector_type(4))) unsigned short us4;
typedef __attribute__((ext_vector_type(8))) unsigned short us8;

__device__ __forceinline__ unsigned short f2bf(float f) {   // RNE f32 -> bf16
  union { float f; unsigned u; } x; x.f = f;
  unsigned r = x.u + 0x7FFFu + ((x.u >> 16) & 1u);
  return (unsigned short)(r >> 16);
}
__device__ __forceinline__ float bf2f(unsigned short h) {
  union { unsigned u; float f; } x; x.u = ((unsigned)h) << 16;
  return x.f;
}

// async global->LDS, 16B per lane; LDS dest is wave-uniform base + lane*16
#define GL2LDS(g, l) __builtin_amdgcn_global_load_lds( \
    (const __attribute__((address_space(1))) unsigned int*)(g), \
    (__attribute__((address_space(3))) unsigned int*)(l), 16, 0, 0)

// raw barrier (no vmcnt drain) + compiler memory fence so LDS ops can't be
// moved across it at compile time
#define BARRIER() do { asm volatile("" ::: "memory"); \
  __builtin_amdgcn_s_barrier(); asm volatile("" ::: "memory"); } while (0)

// ---------------- fused prep (unchanged) ----------------
__global__ __launch_bounds__(256)
void prep(const float* __restrict__ x,
          const float* __restrict__ wq, const float* __restrict__ wk,
          const float* __restrict__ wv, const float* __restrict__ wo,
          unsigned short* __restrict__ xb,
          unsigned short* __restrict__ wqb, unsigned short* __restrict__ wkb,
          unsigned short* __restrict__ vtb, unsigned short* __restrict__ opT)
{
  __shared__ float t[32][33];
  const int b = blockIdx.x;
  if (b < 10240) {
    const float* in; unsigned short* out; int i;
    if (b < 8192)      { in = x;  out = xb;  i = b * 256 + threadIdx.x; }
    else if (b < 9216) { in = wq; out = wqb; i = (b - 8192) * 256 + threadIdx.x; }
    else               { in = wk; out = wkb; i = (b - 9216) * 256 + threadIdx.x; }
    const float4 f = ((const float4*)in)[i];
    us4 v;
    v[0] = f2bf(f.x); v[1] = f2bf(f.y); v[2] = f2bf(f.z); v[3] = f2bf(f.w);
    ((us4*)out)[i] = v;
  } else {
    const float* in = (b < 11264) ? wv : wo;
    unsigned short* out = (b < 11264) ? vtb : opT;
    const int tb = (b < 11264) ? (b - 10240) : (b - 11264);
    const int bx = (tb & 31) * 32, by = (tb >> 5) * 32;
    const int tx = threadIdx.x & 31, ty = threadIdx.x >> 5;
#pragma unroll
    for (int i = 0; i < 32; i += 8)
      t[ty + i][tx] = in[(size_t)(by + ty + i) * 1024 + bx + tx];
    __syncthreads();
#pragma unroll
    for (int i = 0; i < 32; i += 8)
      out[(size_t)(bx + ty + i) * 1024 + by + tx] = f2bf(t[tx][ty + i]);
  }
}

// ---------------- pipelined 128x256 K-loop (BK=64, 8 waves, 3 LDS buffers) ----
// LDS buffer layout (per 48 KiB buffer): A tile [128][64] bf16 at +0 (16 KiB),
// B tile [256][64] bf16 at +16384 (32 KiB). Rows have 128-byte stride; an XOR
// swizzle (byte ^= (row&7)<<4) is applied via inverse-swizzled GLOBAL source
// (global_load_lds writes linearly) and the same XOR on the ds_read address.
// Pipeline: tile t computed from buf[t%3] across 4 phases; tile t+2 staged
// 2 loads/phase into buf[(t+2)%3]; single counted s_waitcnt vmcnt(6) per tile.
__device__ __forceinline__ void kloop256(
    const unsigned short* __restrict__ Abase,
    const unsigned short* __restrict__ Bbase,
    const int lda, const int ldw, const int NT,   // NT = K/64, NT >= 2
    char* smem, f32x4 (&acc)[4][4])
{
  const int tid = threadIdx.x;
  const int lane = tid & 63, wave = tid >> 6;
  const int quad = lane >> 4, l16 = lane & 15;
  const int wm = wave >> 2, wn = wave & 3;          // 2 x 4 wave grid
  const int colS = (quad * 16) ^ ((l16 & 7) << 4);  // swizzled ks=0 byte col
  const int colT = colS ^ 64;                       // ks=1
  const int aRow = (wm * 64 + l16) * 128;
  const int bRow = 16384 + (wn * 64 + l16) * 128;

  // staging: thread covers LDS rows (tid>>3) + 64*i linearly; the global col
  // is pre-swizzled so that swizzled reads see logical data
  const int srow = tid >> 3;
  const int scol = ((tid & 7) ^ (srow & 7)) << 3;   // element offset
  const unsigned short* As = Abase + (size_t)srow * lda + scol;
  const unsigned short* Bs = Bbase + (size_t)srow * ldw + scol;
  const size_t ldaB = (size_t)lda << 6;             // 64 rows
  const size_t ldwB = (size_t)ldw << 6;

  char* cur = smem;
  char* nx1 = smem + 49152;
  char* nx2 = smem + 98304;

  // prologue: stage tiles 0 and 1
  GL2LDS(As,                 cur +         tid * 16);
  GL2LDS(As + ldaB,          cur +  8192 + tid * 16);
  GL2LDS(Bs,                 cur + 16384 + tid * 16);
  GL2LDS(Bs + ldwB,          cur + 24576 + tid * 16);
  GL2LDS(Bs + 2 * ldwB,      cur + 32768 + tid * 16);
  GL2LDS(Bs + 3 * ldwB,      cur + 40960 + tid * 16);
  GL2LDS(As + 64,            nx1 +         tid * 16);
  GL2LDS(As + 64 + ldaB,     nx1 +  8192 + tid * 16);
  GL2LDS(Bs + 64,            nx1 + 16384 + tid * 16);
  GL2LDS(Bs + 64 + ldwB,     nx1 + 24576 + tid * 16);
  GL2LDS(Bs + 64 + 2 * ldwB, nx1 + 32768 + tid * 16);
  GL2LDS(Bs + 64 + 3 * ldwB, nx1 + 40960 + tid * 16);
  asm volatile("s_waitcnt vmcnt(0)" ::: "memory");
  __builtin_amdgcn_s_barrier();

  int kk = 128;
  for (int t = 0; t < NT; ++t) {
    const bool pf = (t + 2 < NT);
    bf16x8 af[4][2], bf[4][2];

    // ---- phase 0: stage A(t+2); read a01/b01; MFMA m01 x n01
    if (pf) {
      GL2LDS(As + kk,        nx2 +        tid * 16);
      GL2LDS(As + kk + ldaB, nx2 + 8192 + tid * 16);
    }
#pragma unroll
    for (int m = 0; m < 2; ++m) {
      af[m][0] = *(const bf16x8*)(cur + aRow + m * 2048 + colS);
      af[m][1] = *(const bf16x8*)(cur + aRow + m * 2048 + colT);
    }
#pragma unroll
    for (int n = 0; n < 2; ++n) {
      bf[n][0] = *(const bf16x8*)(cur + bRow + n * 2048 + colS);
      bf[n][1] = *(const bf16x8*)(cur + bRow + n * 2048 + colT);
    }
    __builtin_amdgcn_s_setprio(1);
#pragma unroll
    for (int m = 0; m < 2; ++m)
#pragma unroll
      for (int n = 0; n < 2; ++n)
#pragma unroll
        for (int ks = 0; ks < 2; ++ks)
          acc[m][n] = __builtin_amdgcn_mfma_f32_16x16x32_bf16(af[m][ks], bf[n][ks], acc[m][n], 0, 0, 0);
    __builtin_amdgcn_s_setprio(0);
    BARRIER();

    // ---- phase 1: stage B rows 0-127 of (t+2); read b23; MFMA m01 x n23
    if (pf) {
      GL2LDS(Bs + kk,        nx2 + 16384 + tid * 16);
      GL2LDS(Bs + kk + ldwB, nx2 + 24576 + tid * 16);
    }
#pragma unroll
    for (int n = 2; n < 4; ++n) {
      bf[n][0] = *(const bf16x8*)(cur + bRow + n * 2048 + colS);
      bf[n][1] = *(const bf16x8*)(cur + bRow + n * 2048 + colT);
    }
    __builtin_amdgcn_s_setprio(1);
#pragma unroll
    for (int m = 0; m < 2; ++m)
#pragma unroll
      for (int n = 2; n < 4; ++n)
#pragma unroll
        for (int ks = 0; ks < 2; ++ks)
          acc[m][n] = __builtin_amdgcn_mfma_f32_16x16x32_bf16(af[m][ks], bf[n][ks], acc[m][n], 0, 0, 0);
    __builtin_amdgcn_s_setprio(0);
    BARRIER();

    // ---- phase 2: stage B rows 128-255 of (t+2); read a23; MFMA m23 x n23
    if (pf) {
      GL2LDS(Bs + kk + 2 * ldwB, nx2 + 32768 + tid * 16);
      GL2LDS(Bs + kk + 3 * ldwB, nx2 + 40960 + tid * 16);
    }
#pragma unroll
    for (int m = 2; m < 4; ++m) {
      af[m][0] = *(const bf16x8*)(cur + aRow + m * 2048 + colS);
      af[m][1] = *(const bf16x8*)(cur + aRow + m * 2048 + colT);
    }
    __builtin_amdgcn_s_setprio(1);
#pragma unroll
    for (int m = 2; m < 4; ++m)
#pragma unroll
      for (int n = 2; n < 4; ++n)
#pragma unroll
        for (int ks = 0; ks < 2; ++ks)
          acc[m][n] = __builtin_amdgcn_mfma_f32_16x16x32_bf16(af[m][ks], bf[n][ks], acc[m][n], 0, 0, 0);
    __builtin_amdgcn_s_setprio(0);
    BARRIER();

    // ---- phase 3: MFMA m23 x n01 (no reads); counted gate; rotate buffers
    __builtin_amdgcn_s_setprio(1);
#pragma unroll
    for (int m = 2; m < 4; ++m)
#pragma unroll
      for (int n = 0; n < 2; ++n)
#pragma unroll
        for (int ks = 0; ks < 2; ++ks)
          acc[m][n] = __builtin_amdgcn_mfma_f32_16x16x32_bf16(af[m][ks], bf[n][ks], acc[m][n], 0, 0, 0);
    __builtin_amdgcn_s_setprio(0);
    if (pf) asm volatile("s_waitcnt vmcnt(6)" ::: "memory");   // t+1 landed; t+2 in flight
    else    asm volatile("s_waitcnt vmcnt(0)" ::: "memory");   // tail
    __builtin_amdgcn_s_barrier();

    kk += 64;
    char* tp = cur; cur = nx1; nx1 = nx2; nx2 = tp;
  }
}

// ---------------- epilogues (LDS-staged coalesced stores) ----------------
__device__ __forceinline__ void epi_bf16(const f32x4 (&acc)[4][4], unsigned short* __restrict__ C,
                                         int ldc, int gr0, int gc0, char* smem)
{
  const int tid = threadIdx.x;
  const int lane = tid & 63, wave = tid >> 6;
  const int quad = lane >> 4, l16 = lane & 15;
  unsigned short* patch = (unsigned short*)smem + wave * (16 * 72);
#pragma unroll
  for (int mt = 0; mt < 4; ++mt) {
#pragma unroll
    for (int nt = 0; nt < 4; ++nt)
#pragma unroll
      for (int r = 0; r < 4; ++r)
        patch[(quad * 4 + r) * 72 + nt * 16 + l16] = f2bf(acc[mt][nt][r]);
    __builtin_amdgcn_wave_barrier();
#pragma unroll
    for (int j = 0; j < 2; ++j) {
      const int rr = j * 8 + (lane >> 3);
      us8 v = *(const us8*)&patch[rr * 72 + (lane & 7) * 8];
      *(us8*)&C[(size_t)(gr0 + mt * 16 + rr) * ldc + gc0 + (lane & 7) * 8] = v;
    }
    __builtin_amdgcn_wave_barrier();
  }
}

__device__ __forceinline__ void epi_f32(const f32x4 (&acc)[4][4], float* __restrict__ C,
                                        int ldc, int gr0, int gc0, char* smem)
{
  const int tid = threadIdx.x;
  const int lane = tid & 63, wave = tid >> 6;
  const int quad = lane >> 4, l16 = lane & 15;
  float* patch = (float*)smem + wave * (16 * 68);
#pragma unroll
  for (int mt = 0; mt < 4; ++mt) {
#pragma unroll
    for (int nt = 0; nt < 4; ++nt)
#pragma unroll
      for (int r = 0; r < 4; ++r)
        patch[(quad * 4 + r) * 68 + nt * 16 + l16] = acc[mt][nt][r];
    __builtin_amdgcn_wave_barrier();
#pragma unroll
    for (int j = 0; j < 4; ++j) {
      const int rr = j * 4 + (lane >> 4);
      float4 v = *(const float4*)&patch[rr * 68 + (lane & 15) * 4];
      *(float4*)&C[(size_t)(gr0 + mt * 16 + rr) * ldc + gc0 + (lane & 15) * 4] = v;
    }
    __builtin_amdgcn_wave_barrier();
  }
}

// ---------------- fused QKV' projection (BM=128, BN=256) ----------------
// blockIdx.x in [0,12): wsel = x>>2, n0 = (x&3)*256.
// wsel 0: Q, 1: K, 2: V' = x @ Wct^T stored transposed VT[b][j][s].
__global__ __launch_bounds__(512, 2)
void gemm_qkv(const unsigned short* __restrict__ xb,
              const unsigned short* __restrict__ wq, const unsigned short* __restrict__ wk,
              const unsigned short* __restrict__ wct,
              unsigned short* __restrict__ Q, unsigned short* __restrict__ Kb,
              unsigned short* __restrict__ VT)
{
  const int m0 = blockIdx.y * 128;
  const int wsel = blockIdx.x >> 2;
  const int n0 = (blockIdx.x & 3) * 256;
  const unsigned short* W = (wsel == 0) ? wq : (wsel == 1) ? wk : wct;

  __shared__ __align__(16) char smem[147456];
  f32x4 acc[4][4] = {};
  kloop256(xb + (size_t)m0 * 1024, W + (size_t)n0 * 1024, 1024, 1024, 16, smem, acc);

  __syncthreads();
  const int tid = threadIdx.x;
  const int lane = tid & 63, wave = tid >> 6;
  const int quad = lane >> 4, l16 = lane & 15;
  const int wm = wave >> 2, wn = wave & 3;
  const int gr0 = m0 + wm * 64, gc0 = n0 + wn * 64;
  if (wsel == 2) {
#pragma unroll
    for (int mt = 0; mt < 4; ++mt)
#pragma unroll
      for (int nt = 0; nt < 4; ++nt) {
        const int gr = gr0 + mt * 16 + quad * 4;
        const int gc = gc0 + nt * 16 + l16;
        us4 v;
#pragma unroll
        for (int r = 0; r < 4; ++r) v[r] = f2bf(acc[mt][nt][r]);
        const int b = gr >> 11, s = gr & 2047;
        *(us4*)(VT + (size_t)b * (1024 * 2048) + (size_t)gc * 2048 + s) = v;
      }
  } else {
    epi_bf16(acc, (wsel == 0) ? Q : Kb, 1024, gr0, gc0, smem);
  }
}

// ---------------- generic bf16 GEMM: C = A @ W^T (BM=128, BN=256) ----------
// MODE 0: C bf16; MODE 1: C f32. CAUSAL: block skip. PVLIM: Keff = m0+128.
template<int MODE, bool CAUSAL, bool PVLIM>
__global__ __launch_bounds__(512, 2)
void gemm_bt(const unsigned short* __restrict__ A, const unsigned short* __restrict__ W,
             void* __restrict__ Cv, int lda, int ldw, int ldc, int K,
             long long sAz, long long sWz, long long sCz)
{
  const int m0 = blockIdx.y * 128;
  const int n0 = blockIdx.x * 256;
  if (CAUSAL && n0 > m0 + 127) return;
  const int z = blockIdx.z;
  A += (size_t)z * sAz;
  W += (size_t)z * sWz;

  __shared__ __align__(16) char smem[147456];
  f32x4 acc[4][4] = {};
  const int Keff = PVLIM ? ((m0 + 128 < K) ? (m0 + 128) : K) : K;
  kloop256(A + (size_t)m0 * lda, W + (size_t)n0 * ldw, lda, ldw, Keff >> 6, smem, acc);

  __syncthreads();
  const int wave = threadIdx.x >> 6;
  const int wm = wave >> 2, wn = wave & 3;
  const int gr0 = m0 + wm * 64, gc0 = n0 + wn * 64;
  if (MODE == 0)
    epi_bf16(acc, (unsigned short*)Cv + (size_t)z * sCz, ldc, gr0, gc0, smem);
  else
    epi_f32(acc, (float*)Cv + (size_t)z * sCz, ldc, gr0, gc0, smem);
}

// causal softmax; blockIdx.x = b*2048 + r; valid cols [0,r]; scale 1/32 pre-exp.
__global__ __launch_bounds__(256)
void softmax_causal(unsigned short* __restrict__ SP)
{
  const int gid = blockIdx.x;
  const int r   = gid & 2047;
  const int tid = threadIdx.x;
  unsigned short* row = SP + (size_t)gid * 2048;
  const int n  = r + 1;
  const int nb = ((r >> 7) + 1) << 7;
  const int it = nb >> 8;
  const int rem = nb & 255;

  float vals[8];
  float lmax = -1e30f;
#pragma unroll
  for (int i = 0; i < 8; ++i) {
    const int c = tid + i * 256;
    if (i < it || (i == it && tid < rem)) {
      const float f = bf2f(row[c]);
      vals[i] = f;
      if (c < n) lmax = fmaxf(lmax, f);
    }
  }
#pragma unroll
  for (int m = 32; m; m >>= 1) lmax = fmaxf(lmax, __shfl_xor(lmax, m, 64));
  __shared__ float redm[4], reds[4];
  if ((tid & 63) == 0) redm[tid >> 6] = lmax;
  __syncthreads();
  lmax = fmaxf(fmaxf(redm[0], redm[1]), fmaxf(redm[2], redm[3]));

  float e[8];
  float lsum = 0.f;
#pragma unroll
  for (int i = 0; i < 8; ++i) {
    const int c = tid + i * 256;
    const float ev = (c < n) ? __expf((vals[i] - lmax) * 0.03125f) : 0.f;
    e[i] = ev;
    lsum += ev;
  }
#pragma unroll
  for (int m = 32; m; m >>= 1) lsum += __shfl_xor(lsum, m, 64);
  if ((tid & 63) == 0) reds[tid >> 6] = lsum;
  __syncthreads();
  lsum = reds[0] + reds[1] + reds[2] + reds[3];
  const float inv = 1.f / lsum;
#pragma unroll
  for (int i = 0; i < 8; ++i) {
    const int c = tid + i * 256;
    if (i < it || (i == it && tid < rem))
      row[c] = f2bf(e[i] * inv);
  }
}

extern "C" void kernel_launch(void* const* d_in, const int* in_sizes, int n_in,
                              void* d_out, int out_size, void* d_ws, size_t ws_size,
                              hipStream_t stream)
{
  (void)in_sizes; (void)n_in; (void)out_size; (void)ws_size;
  // dict order: k, q, v, out_proj, x — f32 inputs, f32 output
  const float* wk_f = (const float*)d_in[0];
  const float* wq_f = (const float*)d_in[1];
  const float* wv_f = (const float*)d_in[2];
  const float* wo_f = (const float*)d_in[3];
  const float* x_f  = (const float*)d_in[4];
  float* out = (float*)d_out;

  // ws layout (98 MiB):
  char* p = (char*)d_ws;
  unsigned short* xb   = (unsigned short*)(p);                       // [0,16M)
  unsigned short* Q    = (unsigned short*)(p + ((size_t)16 << 20));  // [16,32M)
  unsigned short* Kb   = (unsigned short*)(p + ((size_t)32 << 20));  // [32,48M)
  unsigned short* VT   = (unsigned short*)(p + ((size_t)48 << 20));  // [48,64M): V'^T [B][j][s]
  unsigned short* SP   = (unsigned short*)(p + ((size_t)64 << 20));  // [64,96M): [B][S][S]
  unsigned short* wqb  = (unsigned short*)(p + ((size_t)64 << 20));  // aliases (dead before scores)
  unsigned short* wkb  = (unsigned short*)(p + ((size_t)66 << 20));
  unsigned short* vtb  = (unsigned short*)(p + ((size_t)68 << 20));  // v^T bf16
  unsigned short* wctb = (unsigned short*)(p + ((size_t)70 << 20));  // Wct = (v^T@out_proj)^T
  unsigned short* opT  = (unsigned short*)(p + ((size_t)96 << 20));  // [96,98M)

  dim3 blk256(256), blk512(512);

  // conversions + transposes (x, wq, wk, v^T, out_proj^T)
  prep<<<dim3(12288), blk256, 0, stream>>>(x_f, wq_f, wk_f, wv_f, wo_f, xb, wqb, wkb, vtb, opT);

  // Wct[j][e] = sum_d out_proj[d][j] * v[d][e], tiny GEMM (M=1024,N=1024,K=1024)
  gemm_bt<0, false, false><<<dim3(4, 8, 1), blk512, 0, stream>>>(opT, vtb, wctb,
      1024, 1024, 1024, 1024, 0, 0, 0);

  // fused Q/K/V' projections: M=8192, N=3*1024, K=1024
  gemm_qkv<<<dim3(12, 64), blk512, 0, stream>>>(xb, wqb, wkb, wctb, Q, Kb, VT);

  // scores (all batches): [B][2048,2048] = Q @ K^T, causal block skip
  gemm_bt<0, true, false><<<dim3(8, 16, 4), blk512, 0, stream>>>(Q, Kb, SP,
      1024, 1024, 2048, 1024,
      (long long)2048 * 1024, (long long)2048 * 1024, (long long)2048 * 2048);

  // P = causal_softmax(scores/32), in place, all batches
  softmax_causal<<<dim3(8192), blk256, 0, stream>>>(SP);

  // out = P @ V' (all batches), K limited to diagonal band, f32 direct to d_out
  gemm_bt<1, false, true><<<dim3(4, 16, 4), blk512, 0, stream>>>(SP, VT, out,
      2048, 2048, 1024, 2048,
      (long long)2048 * 2048, (long long)1024 * 2048, (long long)2048 * 1024);
}